// Round 1
// baseline (169.424 us; speedup 1.0000x reference)
//
#include <hip/hip_runtime.h>

// Ultimus: out = x + softmax((x@Kw+Kb)@(x@Qw+Qb)^T / sqrt(8)) @ (x@Vw+Vb) @ Zw + Zb
// N=8192, D_IN=48, D_ATTN=8, fp32.
//
// ws layout (floats):
//   [0, 65536)        Xks[8192][8]   K-proj pre-scaled by log2(e)/sqrt(8)
//   [65536, 196608)   QVp            Q/V in tiled float4-plane layout:
//                     tile t (256 rows): plane0=q[0:4], plane1=q[4:8],
//                     plane2=v[0:4], plane3=v[4:8]; each plane 256*4 floats.
//   [196608]          qmax2 bits     max_j ||Xq_j||^2 (uint-bits atomicMax)

__global__ __launch_bounds__(256) void proj_kernel(
    const float* __restrict__ x,
    const float* __restrict__ Kw, const float* __restrict__ Kb,
    const float* __restrict__ Qw, const float* __restrict__ Qb,
    const float* __restrict__ Vw, const float* __restrict__ Vb,
    float* __restrict__ Xks, float* __restrict__ QVp,
    unsigned int* __restrict__ qmax2_bits)
{
    __shared__ float xs[32 * 48];
    __shared__ float wAll[3 * 388];   // stride 388 (mod 32 = 4) breaks mat-bank aliasing
    __shared__ float bs[24];
    __shared__ float qn[32 * 8];
    const int tid = threadIdx.x;
    const int r0 = blockIdx.x * 32;

    for (int i = tid; i < 32 * 48; i += 256) xs[i] = x[r0 * 48 + i];
    for (int i = tid; i < 384; i += 256) {
        wAll[i]           = Kw[i];
        wAll[388 + i]     = Qw[i];
        wAll[2 * 388 + i] = Vw[i];
    }
    if (tid < 8)       bs[tid] = Kb[tid];
    else if (tid < 16) bs[tid] = Qb[tid - 8];
    else if (tid < 24) bs[tid] = Vb[tid - 16];
    __syncthreads();

    const float kscale = 0.51008732149f;  // (1/sqrt(8)) * log2(e)
    for (int e = tid; e < 768; e += 256) {
        int r = e / 24;
        int c = e - r * 24;
        int mat = c >> 3, col = c & 7;
        const float* w  = &wAll[mat * 388 + col];
        const float* xr = &xs[r * 48];
        float s = bs[c];
        #pragma unroll
        for (int k = 0; k < 48; k++) s = fmaf(xr[k], w[k * 8], s);
        int j = r0 + r;
        if (mat == 0) {
            Xks[j * 8 + col] = s * kscale;
        } else {
            int plane = (mat - 1) * 2 + (col >> 2);
            QVp[(j >> 8) * 4096 + plane * 1024 + (j & 255) * 4 + (col & 3)] = s;
            if (mat == 1) qn[r * 8 + col] = s;
        }
    }
    __syncthreads();

    if (tid < 32) {
        float n2 = 0.f;
        #pragma unroll
        for (int c = 0; c < 8; c++) n2 = fmaf(qn[tid * 8 + c], qn[tid * 8 + c], n2);
        #pragma unroll
        for (int off = 16; off > 0; off >>= 1)
            n2 = fmaxf(n2, __shfl_xor(n2, off, 64));
        if (tid == 0) atomicMax(qmax2_bits, __float_as_uint(n2));  // n2 >= 0: bit order ok
    }
}

__global__ __launch_bounds__(256) void attn_kernel(
    const float* __restrict__ x,
    const float* __restrict__ Zw, const float* __restrict__ Zb,
    const float* __restrict__ Xks, const float* __restrict__ QVp,
    const unsigned int* __restrict__ qmax2_bits,
    float* __restrict__ out)
{
    __shared__ float4 tile[1024];      // 16 KB: planes q.lo | q.hi | v.lo | v.hi, 256 rows
    __shared__ float Zs[32 * 8];
    __shared__ float zw_s[8 * 48];
    __shared__ float zb_s[48];

    const int tid  = threadIdx.x;
    const int wave = tid >> 6, lane = tid & 63;
    const int r0b  = blockIdx.x * 32;
    const int rw0  = r0b + wave * 8;   // this wave's 8 rows

    for (int i = tid; i < 384; i += 256) zw_s[i] = Zw[i];
    if (tid < 48) zb_s[tid] = Zb[tid];

    const float qmax2 = __uint_as_float(*qmax2_bits);

    float ks[8][8], sinit[8], l[8], acc[8][8];
    #pragma unroll
    for (int r = 0; r < 8; r++) {
        float kn2 = 0.f;
        #pragma unroll
        for (int c = 0; c < 8; c++) {
            ks[r][c] = Xks[(rw0 + r) * 8 + c];
            kn2 = fmaf(ks[r][c], ks[r][c], kn2);
        }
        sinit[r] = -sqrtf(kn2 * qmax2);  // Cauchy-Schwarz: s_ij <= -sinit, no overflow
        l[r] = 0.f;
        #pragma unroll
        for (int c = 0; c < 8; c++) acc[r][c] = 0.f;
    }

    const float4* gQ = (const float4*)QVp;
    float4 stage[4];
    #pragma unroll
    for (int i = 0; i < 4; i++) stage[i] = gQ[tid + i * 256];

    for (int t = 0; t < 32; t++) {
        __syncthreads();
        #pragma unroll
        for (int i = 0; i < 4; i++) tile[tid + i * 256] = stage[i];
        __syncthreads();
        if (t < 31) {  // prefetch next tile; waitcnt lands at next iteration's writes
            #pragma unroll
            for (int i = 0; i < 4; i++) stage[i] = gQ[(t + 1) * 1024 + tid + i * 256];
        }
        #pragma unroll
        for (int it = 0; it < 4; it++) {
            const int jl = it * 64 + lane;
            const float4 qlo = tile[jl],       qhi = tile[256 + jl];
            const float4 vlo = tile[512 + jl], vhi = tile[768 + jl];
            #pragma unroll
            for (int r = 0; r < 8; r++) {
                float s = sinit[r];
                s = fmaf(ks[r][0], qlo.x, s); s = fmaf(ks[r][1], qlo.y, s);
                s = fmaf(ks[r][2], qlo.z, s); s = fmaf(ks[r][3], qlo.w, s);
                s = fmaf(ks[r][4], qhi.x, s); s = fmaf(ks[r][5], qhi.y, s);
                s = fmaf(ks[r][6], qhi.z, s); s = fmaf(ks[r][7], qhi.w, s);
                const float p = __builtin_amdgcn_exp2f(s);
                l[r] += p;
                acc[r][0] = fmaf(p, vlo.x, acc[r][0]);
                acc[r][1] = fmaf(p, vlo.y, acc[r][1]);
                acc[r][2] = fmaf(p, vlo.z, acc[r][2]);
                acc[r][3] = fmaf(p, vlo.w, acc[r][3]);
                acc[r][4] = fmaf(p, vhi.x, acc[r][4]);
                acc[r][5] = fmaf(p, vhi.y, acc[r][5]);
                acc[r][6] = fmaf(p, vhi.z, acc[r][6]);
                acc[r][7] = fmaf(p, vhi.w, acc[r][7]);
            }
        }
    }

    // 64-lane butterfly sum (no max merging needed: shared exponent shift per row)
    #pragma unroll
    for (int m = 1; m < 64; m <<= 1) {
        #pragma unroll
        for (int r = 0; r < 8; r++) {
            l[r] += __shfl_xor(l[r], m, 64);
            #pragma unroll
            for (int c = 0; c < 8; c++) acc[r][c] += __shfl_xor(acc[r][c], m, 64);
        }
    }
    if (lane == 0) {
        #pragma unroll
        for (int r = 0; r < 8; r++) {
            const float inv = 1.0f / l[r];
            #pragma unroll
            for (int c = 0; c < 8; c++) Zs[(wave * 8 + r) * 8 + c] = acc[r][c] * inv;
        }
    }
    __syncthreads();

    // epilogue: out = x + Z @ Zw + Zb
    for (int e = tid; e < 32 * 48; e += 256) {
        const int r = e / 48, c = e - r * 48;
        float o = x[r0b * 48 + e] + zb_s[c];
        #pragma unroll
        for (int k = 0; k < 8; k++) o = fmaf(Zs[r * 8 + k], zw_s[k * 48 + c], o);
        out[r0b * 48 + e] = o;
    }
}

extern "C" void kernel_launch(void* const* d_in, const int* in_sizes, int n_in,
                              void* d_out, int out_size, void* d_ws, size_t ws_size,
                              hipStream_t stream) {
    const float* x  = (const float*)d_in[0];
    const float* Kw = (const float*)d_in[1];
    const float* Kb = (const float*)d_in[2];
    const float* Qw = (const float*)d_in[3];
    const float* Qb = (const float*)d_in[4];
    const float* Vw = (const float*)d_in[5];
    const float* Vb = (const float*)d_in[6];
    const float* Zw = (const float*)d_in[7];
    const float* Zb = (const float*)d_in[8];
    float* out = (float*)d_out;

    float* ws = (float*)d_ws;
    float* Xks = ws;
    float* QVp = ws + 65536;
    unsigned int* qmax2_bits = (unsigned int*)(ws + 196608);

    hipMemsetAsync(qmax2_bits, 0, sizeof(unsigned int), stream);
    proj_kernel<<<256, 256, 0, stream>>>(x, Kw, Kb, Qw, Qb, Vw, Vb, Xks, QVp, qmax2_bits);
    attn_kernel<<<256, 256, 0, stream>>>(x, Zw, Zb, Xks, QVp, qmax2_bits, out);
}

// Round 2
// 156.132 us; speedup vs baseline: 1.0851x; 1.0851x over previous
//
#include <hip/hip_runtime.h>

// Ultimus: out = x + softmax((x@Kw+Kb)@(x@Qw+Qb)^T / sqrt(8)) @ (x@Vw+Vb) @ Zw + Zb
// N=8192, D_IN=48, D_ATTN=8, fp32.
//
// Bound-softmax: exponent shift sinit[r] = -||k_r||*max_j||q_j|| (Cauchy-Schwarz)
// is row-global, so partial (acc,l) over disjoint j-chunks add exactly -> j-split
// across blocks for occupancy (round 1 was 1 wave/SIMD, VALUBusy 26%).
//
// ws layout (floats):
//   [0, 65536)          Xks[8192][8]   K-proj pre-scaled by log2(e)/sqrt(8)
//   [65536, 196608)     QVp            tiled float4-plane layout per 256-row tile
//   [196608]            qmax2 bits     max_j ||q_j||^2 (uint-bits atomicMax)
//   [196864, +393216)   part[4][8192][12]  per-chunk partial acc[0:8], l at [8]

#define PART_OFF 196864

__global__ __launch_bounds__(256) void proj_kernel(
    const float* __restrict__ x,
    const float* __restrict__ Kw, const float* __restrict__ Kb,
    const float* __restrict__ Qw, const float* __restrict__ Qb,
    const float* __restrict__ Vw, const float* __restrict__ Vb,
    float* __restrict__ Xks, float* __restrict__ QVp,
    unsigned int* __restrict__ qmax2_bits)
{
    __shared__ float xs[32 * 49];     // stride 49: 8 rows/wave -> 8 distinct banks
    __shared__ float wAll[3 * 388];   // stride 388 (mod 32 = 4) spreads the 3 mats
    __shared__ float bs[24];
    __shared__ float qn[32 * 8];
    const int tid = threadIdx.x;
    const int r0 = blockIdx.x * 32;

    for (int i = tid; i < 1536; i += 256) {
        int r = i / 48, c = i - r * 48;
        xs[r * 49 + c] = x[r0 * 48 + i];
    }
    for (int i = tid; i < 384; i += 256) {
        wAll[i]       = Kw[i];
        wAll[388 + i] = Qw[i];
        wAll[776 + i] = Vw[i];
    }
    if (tid < 8)       bs[tid] = Kb[tid];
    else if (tid < 16) bs[tid] = Qb[tid - 8];
    else if (tid < 24) bs[tid] = Vb[tid - 16];
    __syncthreads();

    // thread = (row rl, col-group g): computes cols 3g..3g+2 of row r0+rl
    const int rl = tid >> 3;
    const int g  = tid & 7;
    const int c0 = 3 * g;
    const float* xr = &xs[rl * 49];
    const float* w0 = &wAll[((c0 + 0) >> 3) * 388 + ((c0 + 0) & 7)];
    const float* w1 = &wAll[((c0 + 1) >> 3) * 388 + ((c0 + 1) & 7)];
    const float* w2 = &wAll[((c0 + 2) >> 3) * 388 + ((c0 + 2) & 7)];
    float a0 = bs[c0], a1 = bs[c0 + 1], a2 = bs[c0 + 2];
    #pragma unroll
    for (int k = 0; k < 48; k++) {
        const float xv = xr[k];
        a0 = fmaf(xv, w0[k * 8], a0);
        a1 = fmaf(xv, w1[k * 8], a1);
        a2 = fmaf(xv, w2[k * 8], a2);
    }

    const float kscale = 0.51008732149f;  // (1/sqrt(8)) * log2(e)
    const int row = r0 + rl;
    float av[3] = {a0, a1, a2};
    #pragma unroll
    for (int j = 0; j < 3; j++) {
        const int c = c0 + j;
        const int mat = c >> 3, col = c & 7;
        const float s = av[j];
        if (mat == 0) {
            Xks[row * 8 + col] = s * kscale;
        } else {
            const int plane = (mat - 1) * 2 + (col >> 2);
            QVp[(row >> 8) * 4096 + plane * 1024 + (row & 255) * 4 + (col & 3)] = s;
            if (mat == 1) qn[rl * 8 + col] = s;
        }
    }
    __syncthreads();

    if (tid < 32) {
        float n2 = 0.f;
        #pragma unroll
        for (int c = 0; c < 8; c++) n2 = fmaf(qn[tid * 8 + c], qn[tid * 8 + c], n2);
        #pragma unroll
        for (int off = 16; off > 0; off >>= 1)
            n2 = fmaxf(n2, __shfl_xor(n2, off, 64));
        if (tid == 0) atomicMax(qmax2_bits, __float_as_uint(n2));  // n2 >= 0: bit order ok
    }
}

__global__ __launch_bounds__(256) void attn_kernel(
    const float* __restrict__ Xks, const float* __restrict__ QVp,
    const unsigned int* __restrict__ qmax2_bits,
    float* __restrict__ part)
{
    __shared__ float4 tile[1024];  // 16 KB: planes q.lo | q.hi | v.lo | v.hi, 256 rows

    const int tid   = threadIdx.x;
    const int wave  = tid >> 6, lane = tid & 63;
    const int rg    = blockIdx.x & 255;   // row-group: 32 rows
    const int chunk = blockIdx.x >> 8;    // j-chunk: tiles [chunk*8, chunk*8+8)
    const int rw0   = rg * 32 + wave * 8;

    const float qmax2 = __uint_as_float(*qmax2_bits);

    float ks[8][8], sinit[8], l[8], acc[8][8];
    #pragma unroll
    for (int r = 0; r < 8; r++) {
        float kn2 = 0.f;
        #pragma unroll
        for (int c = 0; c < 8; c++) {
            ks[r][c] = Xks[(rw0 + r) * 8 + c];
            kn2 = fmaf(ks[r][c], ks[r][c], kn2);
        }
        sinit[r] = -sqrtf(kn2 * qmax2);  // s_ij <= -sinit: p in (0,1], no overflow
        l[r] = 0.f;
        #pragma unroll
        for (int c = 0; c < 8; c++) acc[r][c] = 0.f;
    }

    const float4* gQ = (const float4*)QVp + (size_t)chunk * 8 * 1024;
    float4 stage[4];
    #pragma unroll
    for (int i = 0; i < 4; i++) stage[i] = gQ[tid + i * 256];

    for (int t = 0; t < 8; t++) {
        __syncthreads();
        #pragma unroll
        for (int i = 0; i < 4; i++) tile[tid + i * 256] = stage[i];
        __syncthreads();
        if (t < 7) {
            #pragma unroll
            for (int i = 0; i < 4; i++) stage[i] = gQ[(t + 1) * 1024 + tid + i * 256];
        }
        #pragma unroll
        for (int it = 0; it < 4; it++) {
            const int jl = it * 64 + lane;
            const float4 qlo = tile[jl],       qhi = tile[256 + jl];
            const float4 vlo = tile[512 + jl], vhi = tile[768 + jl];
            #pragma unroll
            for (int r = 0; r < 8; r++) {
                float s = sinit[r];
                s = fmaf(ks[r][0], qlo.x, s); s = fmaf(ks[r][1], qlo.y, s);
                s = fmaf(ks[r][2], qlo.z, s); s = fmaf(ks[r][3], qlo.w, s);
                s = fmaf(ks[r][4], qhi.x, s); s = fmaf(ks[r][5], qhi.y, s);
                s = fmaf(ks[r][6], qhi.z, s); s = fmaf(ks[r][7], qhi.w, s);
                const float p = __builtin_amdgcn_exp2f(s);
                l[r] += p;
                acc[r][0] = fmaf(p, vlo.x, acc[r][0]);
                acc[r][1] = fmaf(p, vlo.y, acc[r][1]);
                acc[r][2] = fmaf(p, vlo.z, acc[r][2]);
                acc[r][3] = fmaf(p, vlo.w, acc[r][3]);
                acc[r][4] = fmaf(p, vhi.x, acc[r][4]);
                acc[r][5] = fmaf(p, vhi.y, acc[r][5]);
                acc[r][6] = fmaf(p, vhi.z, acc[r][6]);
                acc[r][7] = fmaf(p, vhi.w, acc[r][7]);
            }
        }
    }

    // 64-lane butterfly sum; shared exponent per row -> pure adds, chunks add too
    #pragma unroll
    for (int m = 1; m < 64; m <<= 1) {
        #pragma unroll
        for (int r = 0; r < 8; r++) {
            l[r] += __shfl_xor(l[r], m, 64);
            #pragma unroll
            for (int c = 0; c < 8; c++) acc[r][c] += __shfl_xor(acc[r][c], m, 64);
        }
    }
    if (lane == 0) {
        float* pr = part + ((size_t)chunk * 8192 + rw0) * 12;
        #pragma unroll
        for (int r = 0; r < 8; r++) {
            #pragma unroll
            for (int c = 0; c < 8; c++) pr[r * 12 + c] = acc[r][c];
            pr[r * 12 + 8] = l[r];
        }
    }
}

__global__ __launch_bounds__(256) void finish_kernel(
    const float* __restrict__ x,
    const float* __restrict__ Zw, const float* __restrict__ Zb,
    const float* __restrict__ part, float* __restrict__ out)
{
    __shared__ float Zs[128 * 9];
    __shared__ float zw_s[384];
    __shared__ float zb_s[48];
    const int tid = threadIdx.x;
    const int r0 = blockIdx.x * 128;

    for (int i = tid; i < 384; i += 256) zw_s[i] = Zw[i];
    if (tid < 48) zb_s[tid] = Zb[tid];

    if (tid < 128) {
        const int row = r0 + tid;
        float a[9];
        #pragma unroll
        for (int c = 0; c < 9; c++) a[c] = 0.f;
        #pragma unroll
        for (int ch = 0; ch < 4; ch++) {
            const float* p = part + ((size_t)ch * 8192 + row) * 12;
            #pragma unroll
            for (int c = 0; c < 9; c++) a[c] += p[c];
        }
        const float inv = 1.0f / a[8];
        #pragma unroll
        for (int c = 0; c < 8; c++) Zs[tid * 9 + c] = a[c] * inv;
    }
    __syncthreads();

    for (int e = tid; e < 128 * 48; e += 256) {
        const int r = e / 48, c = e - r * 48;
        float o = x[r0 * 48 + e] + zb_s[c];
        #pragma unroll
        for (int k = 0; k < 8; k++) o = fmaf(Zs[r * 9 + k], zw_s[k * 48 + c], o);
        out[r0 * 48 + e] = o;
    }
}

extern "C" void kernel_launch(void* const* d_in, const int* in_sizes, int n_in,
                              void* d_out, int out_size, void* d_ws, size_t ws_size,
                              hipStream_t stream) {
    const float* x  = (const float*)d_in[0];
    const float* Kw = (const float*)d_in[1];
    const float* Kb = (const float*)d_in[2];
    const float* Qw = (const float*)d_in[3];
    const float* Qb = (const float*)d_in[4];
    const float* Vw = (const float*)d_in[5];
    const float* Vb = (const float*)d_in[6];
    const float* Zw = (const float*)d_in[7];
    const float* Zb = (const float*)d_in[8];
    float* out = (float*)d_out;

    float* ws = (float*)d_ws;
    float* Xks = ws;
    float* QVp = ws + 65536;
    unsigned int* qmax2_bits = (unsigned int*)(ws + 196608);
    float* part = ws + PART_OFF;

    hipMemsetAsync(qmax2_bits, 0, sizeof(unsigned int), stream);
    proj_kernel<<<256, 256, 0, stream>>>(x, Kw, Kb, Qw, Qb, Vw, Vb, Xks, QVp, qmax2_bits);
    attn_kernel<<<1024, 256, 0, stream>>>(Xks, QVp, qmax2_bits, part);
    finish_kernel<<<64, 256, 0, stream>>>(x, Zw, Zb, part, out);
}